// Round 1
// baseline (866.796 us; speedup 1.0000x reference)
//
#include <hip/hip_runtime.h>
#include <hip/hip_bf16.h>

// SpatialWindowSelfAttention — MI355X gfx950.
// Fast path (needs ws >= 64.5MB): K0 weights->bf16 in ws; K1v2 fused QKV+attn
// (3 blocks/CU: 54.3KB LDS, <=170 VGPR, 9 barriers, bf16 weight loads,
// register-shuffle Q transpose, y->bf16 in ws); K2v2 bf16 projection -> f32 out.
// Fallback path: previous verified kernels (f32 weights, zero workspace).

typedef __bf16 bf16;
typedef bf16 bf16x2 __attribute__((ext_vector_type(2)));
typedef bf16 bf16x4 __attribute__((ext_vector_type(4)));
typedef bf16 bf16x8 __attribute__((ext_vector_type(8)));
typedef float f32x4 __attribute__((ext_vector_type(4)));
typedef int i32x4 __attribute__((ext_vector_type(4)));

#define MFMA16(a, b, c) __builtin_amdgcn_mfma_f32_16x16x32_bf16(a, b, c, 0, 0, 0)

__device__ __forceinline__ bf16x8 cvt8(const float* p) {  // 32B-aligned f32 -> bf16x8
  f32x4 lo = *(const f32x4*)p;
  f32x4 hi = *(const f32x4*)(p + 4);
  bf16x8 r;
#pragma unroll
  for (int j = 0; j < 4; j++) { r[j] = (bf16)lo[j]; r[j + 4] = (bf16)hi[j]; }
  return r;
}
__device__ __forceinline__ bf16x8 lds8(const bf16* p) {  // 8B-aligned LDS pair
  bf16x4 lo = *(const bf16x4*)p;
  bf16x4 hi = *(const bf16x4*)(p + 4);
  return __builtin_shufflevector(lo, hi, 0, 1, 2, 3, 4, 5, 6, 7);
}
__device__ __forceinline__ int pack2(float a, float b) {  // 2 f32 -> bf16x2 dword
  bf16x2 t; t[0] = (bf16)a; t[1] = (bf16)b;
  return __builtin_bit_cast(int, t);
}

// ======================= FAST PATH =======================

// K0: convert wqkv_w [768*256] and wp_w [256*256] f32 -> bf16 into ws.
__global__ __launch_bounds__(256) void cvt_weights(
    const float* __restrict__ wq, const float* __restrict__ wp, bf16* __restrict__ dst) {
  const int g = (blockIdx.x * 256 + threadIdx.x) * 4;
  const float* src = (g < 196608) ? (wq + g) : (wp + (g - 196608));
  const f32x4 v = *(const f32x4*)src;
  bf16x4 o;
#pragma unroll
  for (int j = 0; j < 4; ++j) o[j] = (bf16)v[j];
  *(bf16x4*)(dst + g) = o;
}

// Per-wave LDS scratch (elements): Ks[64][36]@0 (P-half overlays after kf reads),
// Vt[32][72]@2304. Total 4608 elems = 9216B/wave.
#define V2_KS 0
#define V2_VT 2304
#define V2_UNI 4608

// K1 v2: per-window fused QKV projection + window attention -> y (bf16) in ws.
// W-major MFMA: A = wqkv rows (bf16, direct from L2), B = x window (LDS bf16).
// C layout: ch = mi*16+quad*4+r, tok = nj*16+lr.
__global__ __launch_bounds__(256, 3) void fused_qkv_attn_v2(
    const float* __restrict__ x, const bf16* __restrict__ wq,
    const float* __restrict__ wqkv_b, const float* __restrict__ bias_table,
    bf16* __restrict__ yb) {
  __shared__ __align__(16) bf16 xs[64][136];     // x chunk: 64 tok x 128 ch (+8 pad)
  __shared__ __align__(16) bf16 uni[4][V2_UNI];  // per-wave scratch

  const int tid = threadIdx.x;
  const int wave = tid >> 6, lane = tid & 63;
  const int lr = lane & 15, quad = lane >> 4;
  const int win = blockIdx.x;                    // [0,2048)
  const int batch = win >> 10, wy = (win >> 5) & 31, wx = win & 31;
  const int base = batch * 65536 + wy * 2048 + wx * 8;
  bf16* const U = &uni[wave][0];

  const f32x4 zero = {0.f, 0.f, 0.f, 0.f};
  const float scale = 0.17677669529663687f;  // 1/sqrt(32)

  f32x4 acc[6][4];

  for (int ph = 0; ph < 4; ++ph) {             // phase = (rep, kc): 2 heads x 2 K-chunks
    const int rep = ph >> 1, kc = ph & 1;
    const int h = wave * 2 + rep;
    if (ph) __syncthreads();                   // prior xs reads done before overwrite
    // ---- stage x chunk [64 tok][128 ch] as bf16 (fully coalesced 512B runs) ----
#pragma unroll
    for (int i = 0; i < 8; ++i) {
      const int e = i * 1024 + tid * 4;
      const int tok = e >> 7, c = e & 127;
      const float* xp = x + (size_t)(base + (tok >> 3) * 256 + (tok & 7)) * 256 + kc * 128 + c;
      const f32x4 v = *(const f32x4*)xp;
      bf16x4 o;
#pragma unroll
      for (int j = 0; j < 4; ++j) o[j] = (bf16)v[j];
      *(bf16x4*)&xs[tok][c] = o;
    }
    __syncthreads();

    const int cb0 = h * 32;
    const int cbase[6] = {cb0, cb0 + 16, 256 + cb0, 256 + cb0 + 16, 512 + cb0, 512 + cb0 + 16};
    if (!kc) {
#pragma unroll
      for (int mi = 0; mi < 6; ++mi)
#pragma unroll
        for (int nj = 0; nj < 4; ++nj) acc[mi][nj] = zero;
    }
#pragma unroll
    for (int kkk = 0; kkk < 128; kkk += 32) {
      bf16x8 a[6], b[4];
#pragma unroll
      for (int mi = 0; mi < 6; ++mi)
        a[mi] = *(const bf16x8*)&wq[(size_t)(cbase[mi] + lr) * 256 + kc * 128 + kkk + quad * 8];
#pragma unroll
      for (int nj = 0; nj < 4; ++nj)
        b[nj] = *(const bf16x8*)&xs[nj * 16 + lr][kkk + quad * 8];
#pragma unroll
      for (int mi = 0; mi < 6; ++mi)
#pragma unroll
        for (int nj = 0; nj < 4; ++nj) acc[mi][nj] = MFMA16(a[mi], b[nj], acc[mi][nj]);
    }
    if (!kc) continue;

    // ================= attention for head h =================
    // bias add (f32x4 from L2)
#pragma unroll
    for (int mi = 0; mi < 6; ++mi) {
      const f32x4 bb = *(const f32x4*)&wqkv_b[cbase[mi] + quad * 4];
#pragma unroll
      for (int nj = 0; nj < 4; ++nj)
#pragma unroll
        for (int r = 0; r < 4; ++r) acc[mi][nj][r] += bb[r];
    }
    // V -> Vt [32 d][72] (token innermost, for PV B-fragments)
#pragma unroll
    for (int mi = 4; mi < 6; ++mi)
#pragma unroll
      for (int nj = 0; nj < 4; ++nj)
#pragma unroll
        for (int r = 0; r < 4; ++r)
          U[V2_VT + ((mi & 1) * 16 + quad * 4 + r) * 72 + nj * 16 + lr] = (bf16)acc[mi][nj][r];
    // K -> Ks [64 tok][36], 8B vector writes (d-consecutive per lane)
#pragma unroll
    for (int mi = 2; mi < 4; ++mi)
#pragma unroll
      for (int nj = 0; nj < 4; ++nj) {
        bf16x4 kv;
#pragma unroll
        for (int r = 0; r < 4; ++r) kv[r] = (bf16)acc[mi][nj][r];
        *(bf16x4*)&U[V2_KS + (nj * 16 + lr) * 36 + (mi & 1) * 16 + quad * 4] = kv;
      }
    // Q -> MFMA B-fragment layout entirely in-register:
    // dest lane (quad,lr) needs Q[tok=qt*16+lr][d=quad*8+j]; source value lives at
    // lane ((quad&1)*32 [+16]) + lr as pack(r0,r1)/pack(r2,r3) of acc[quad>>1][qt].
    int pkA[2][4], pkB[2][4];
#pragma unroll
    for (int mi = 0; mi < 2; ++mi)
#pragma unroll
      for (int nj = 0; nj < 4; ++nj) {
        pkA[mi][nj] = pack2(acc[mi][nj][0], acc[mi][nj][1]);
        pkB[mi][nj] = pack2(acc[mi][nj][2], acc[mi][nj][3]);
      }
    const int L0 = ((quad & 1) << 5) | lr;
    const int L1 = L0 + 16;
    const bool hiq = quad >= 2;  // selects mi = quad>>1
    bf16x8 qf[4];
#pragma unroll
    for (int qt = 0; qt < 4; ++qt) {
      const int a0 = __shfl(pkA[0][qt], L0, 64), a1 = __shfl(pkA[1][qt], L0, 64);
      const int b0 = __shfl(pkB[0][qt], L0, 64), b1 = __shfl(pkB[1][qt], L0, 64);
      const int a0h = __shfl(pkA[0][qt], L1, 64), a1h = __shfl(pkA[1][qt], L1, 64);
      const int b0h = __shfl(pkB[0][qt], L1, 64), b1h = __shfl(pkB[1][qt], L1, 64);
      const i32x4 w = {hiq ? a1 : a0, hiq ? b1 : b0, hiq ? a1h : a0h, hiq ? b1h : b0h};
      qf[qt] = __builtin_bit_cast(bf16x8, w);
    }
    bf16x8 kf[4];
#pragma unroll
    for (int kt = 0; kt < 4; ++kt) kf[kt] = lds8(&U[V2_KS + (kt * 16 + lr) * 36 + quad * 8]);
    // S^T[ktok][qtok] = K Q^T (swapped so softmax rows are mostly lane-local)
    f32x4 s[4][4];
#pragma unroll
    for (int kt = 0; kt < 4; ++kt)
#pragma unroll
      for (int qt = 0; qt < 4; ++qt) s[kt][qt] = MFMA16(kf[kt], qf[qt], zero);
    // scale + relative-position bias: ktok = kt*16+quad*4+r, qtok = qt*16+lr
#pragma unroll
    for (int kt = 0; kt < 4; ++kt)
#pragma unroll
      for (int r = 0; r < 4; ++r) {
        const int ktok = kt * 16 + quad * 4 + r;
#pragma unroll
        for (int qt = 0; qt < 4; ++qt) {
          const int qtok = qt * 16 + lr;
          const int idx = ((qtok >> 3) - (ktok >> 3) + 7) * 15 + (qtok & 7) - (ktok & 7) + 7;
          s[kt][qt][r] = s[kt][qt][r] * scale + bias_table[idx * 8 + h];
        }
      }
    // softmax over k: 16 in-lane values + 2 cross-quad shuffles per q
    float inv[4];
#pragma unroll
    for (int qt = 0; qt < 4; ++qt) {
      float mx = -1e30f;
#pragma unroll
      for (int kt = 0; kt < 4; ++kt)
#pragma unroll
        for (int r = 0; r < 4; ++r) mx = fmaxf(mx, s[kt][qt][r]);
      mx = fmaxf(mx, __shfl_xor(mx, 16, 64));
      mx = fmaxf(mx, __shfl_xor(mx, 32, 64));
      float sum = 0.f;
#pragma unroll
      for (int kt = 0; kt < 4; ++kt)
#pragma unroll
        for (int r = 0; r < 4; ++r) {
          const float e = __expf(s[kt][qt][r] - mx);
          s[kt][qt][r] = e;
          sum += e;
        }
      sum += __shfl_xor(sum, 16, 64);
      sum += __shfl_xor(sum, 32, 64);
      inv[qt] = 1.0f / sum;
    }
    // O = P @ V in two 32-k halves; P-half [64][36] overlays Ks (wave-local, DS in-order)
    f32x4 o[4][2] = {};
#pragma unroll
    for (int kh = 0; kh < 2; ++kh) {
#pragma unroll
      for (int kt2 = 0; kt2 < 2; ++kt2) {
        const int kt = kh * 2 + kt2;
#pragma unroll
        for (int qt = 0; qt < 4; ++qt)
#pragma unroll
          for (int r = 0; r < 4; ++r)
            U[V2_KS + (qt * 16 + lr) * 36 + kt2 * 16 + quad * 4 + r] =
                (bf16)(s[kt][qt][r] * inv[qt]);
      }
      bf16x8 pa[4], vb[2];
#pragma unroll
      for (int mt = 0; mt < 4; ++mt) pa[mt] = lds8(&U[V2_KS + (mt * 16 + lr) * 36 + quad * 8]);
#pragma unroll
      for (int ni = 0; ni < 2; ++ni)
        vb[ni] = *(const bf16x8*)&U[V2_VT + (ni * 16 + lr) * 72 + kh * 32 + quad * 8];
#pragma unroll
      for (int mt = 0; mt < 4; ++mt)
#pragma unroll
        for (int ni = 0; ni < 2; ++ni) o[mt][ni] = MFMA16(pa[mt], vb[ni], o[mt][ni]);
    }
    // store y slice as bf16 into ws
#pragma unroll
    for (int mt = 0; mt < 4; ++mt)
#pragma unroll
      for (int ni = 0; ni < 2; ++ni)
#pragma unroll
        for (int r = 0; r < 4; ++r) {
          const int q = mt * 16 + quad * 4 + r;
          const size_t row = (size_t)(base + (q >> 3) * 256 + (q & 7));
          yb[row * 256 + h * 32 + ni * 16 + lr] = (bf16)o[mt][ni][r];
        }
  }
}

// K2 v2: out[131072,256] f32 = yb(bf16) @ wp_bf16^T + wp_b. Zero LDS, 16 waves/CU.
__global__ __launch_bounds__(256, 4) void proj_v2(
    const bf16* __restrict__ yb, const bf16* __restrict__ wp,
    const float* __restrict__ wp_b, float* __restrict__ out) {
  const int tid = threadIdx.x;
  const int wave = tid >> 6, lane = tid & 63;
  const int lr = lane & 15, quad = lane >> 4;
  const size_t row0 = (size_t)blockIdx.x * 64;
  const int col0 = wave * 64;

  f32x4 acc[4][4] = {};
#pragma unroll
  for (int kk = 0; kk < 256; kk += 32) {
    bf16x8 a[4], b[4];
#pragma unroll
    for (int mt = 0; mt < 4; ++mt)
      a[mt] = *(const bf16x8*)&yb[(row0 + mt * 16 + lr) * 256 + kk + quad * 8];
#pragma unroll
    for (int nt = 0; nt < 4; ++nt)
      b[nt] = *(const bf16x8*)&wp[(size_t)(col0 + nt * 16 + lr) * 256 + kk + quad * 8];
#pragma unroll
    for (int mt = 0; mt < 4; ++mt)
#pragma unroll
      for (int nt = 0; nt < 4; ++nt) acc[mt][nt] = MFMA16(a[mt], b[nt], acc[mt][nt]);
  }
#pragma unroll
  for (int mt = 0; mt < 4; ++mt)
#pragma unroll
    for (int nt = 0; nt < 4; ++nt) {
      const int col = col0 + nt * 16 + lr;
      const float bv = wp_b[col];
#pragma unroll
      for (int r = 0; r < 4; ++r)
        out[(row0 + mt * 16 + quad * 4 + r) * 256 + col] = acc[mt][nt][r] + bv;
    }
}

// ======================= FALLBACK PATH (previous verified kernels) =======================

#define QS_OFF 0
#define KS_OFF 2304
#define VT_OFF 4608
#define PL_OFF 0
#define UNI_SZ 6784

__global__ __launch_bounds__(256) void fused_qkv_attn(
    const float* __restrict__ x, const float* __restrict__ wqkv_w,
    const float* __restrict__ wqkv_b, const float* __restrict__ bias_table,
    float* __restrict__ out) {
  __shared__ bf16 xs[64][72];
  __shared__ bf16 uni[4][UNI_SZ];

  const int tid = threadIdx.x;
  const int wave = tid >> 6, lane = tid & 63;
  const int lr = lane & 15, quad = lane >> 4;
  const int win = blockIdx.x;
  const int batch = win >> 10, wy = (win >> 5) & 31, wx = win & 31;
  const int base = batch * 65536 + wy * 2048 + wx * 8;
  bf16* const U = &uni[wave][0];

  const f32x4 zero = {0.f, 0.f, 0.f, 0.f};
  const float scale = 0.17677669529663687f;

  for (int rep = 0; rep < 2; rep++) {
    const int h = wave * 2 + rep;
    const int cb[6] = {h * 32,       h * 32 + 16,
                       256 + h * 32, 256 + h * 32 + 16,
                       512 + h * 32, 512 + h * 32 + 16};

    f32x4 acc[4][6] = {};
    for (int kc = 0; kc < 4; kc++) {
      __syncthreads();
      {
        const int t = tid >> 2, c0 = (tid & 3) * 16;
        const float* xp = x + (size_t)(base + (t >> 3) * 256 + (t & 7)) * 256 + kc * 64 + c0;
        *(bf16x8*)&xs[t][c0] = cvt8(xp);
        *(bf16x8*)&xs[t][c0 + 8] = cvt8(xp + 8);
      }
      __syncthreads();
#pragma unroll
      for (int k2 = 0; k2 < 64; k2 += 32) {
        bf16x8 a[4], b[6];
#pragma unroll
        for (int mi = 0; mi < 4; mi++) a[mi] = lds8(&xs[mi * 16 + lr][k2 + quad * 8]);
#pragma unroll
        for (int nj = 0; nj < 6; nj++)
          b[nj] = cvt8(wqkv_w + (size_t)(cb[nj] + lr) * 256 + kc * 64 + k2 + quad * 8);
#pragma unroll
        for (int mi = 0; mi < 4; mi++)
#pragma unroll
          for (int nj = 0; nj < 6; nj++) acc[mi][nj] = MFMA16(a[mi], b[nj], acc[mi][nj]);
      }
    }

#pragma unroll
    for (int nj = 0; nj < 6; nj++) {
      const float bv = wqkv_b[cb[nj] + lr];
#pragma unroll
      for (int mi = 0; mi < 4; mi++)
#pragma unroll
        for (int r = 0; r < 4; r++) {
          const int tok = mi * 16 + quad * 4 + r;
          const float v = acc[mi][nj][r] + bv;
          if (nj < 2)      U[QS_OFF + tok * 36 + nj * 16 + lr] = (bf16)v;
          else if (nj < 4) U[KS_OFF + tok * 36 + (nj - 2) * 16 + lr] = (bf16)v;
          else             U[VT_OFF + ((nj - 4) * 16 + lr) * 68 + tok] = (bf16)v;
        }
    }

    bf16x8 qf[4], kf[4];
#pragma unroll
    for (int i = 0; i < 4; i++) {
      qf[i] = lds8(&U[QS_OFF + (i * 16 + lr) * 36 + quad * 8]);
      kf[i] = lds8(&U[KS_OFF + (i * 16 + lr) * 36 + quad * 8]);
    }
    f32x4 s[4][4];
#pragma unroll
    for (int mi = 0; mi < 4; mi++)
#pragma unroll
      for (int nj = 0; nj < 4; nj++) s[mi][nj] = MFMA16(qf[mi], kf[nj], zero);

#pragma unroll
    for (int mi = 0; mi < 4; mi++)
#pragma unroll
      for (int nj = 0; nj < 4; nj++)
#pragma unroll
        for (int r = 0; r < 4; r++) {
          const int qt = mi * 16 + quad * 4 + r;
          const int kt = nj * 16 + lr;
          const int idx = ((qt >> 3) - (kt >> 3) + 7) * 15 + ((qt & 7) - (kt & 7) + 7);
          s[mi][nj][r] = s[mi][nj][r] * scale + bias_table[idx * 8 + h];
        }

#pragma unroll
    for (int mi = 0; mi < 4; mi++)
#pragma unroll
      for (int r = 0; r < 4; r++) {
        float mx = -1e30f;
#pragma unroll
        for (int nj = 0; nj < 4; nj++) mx = fmaxf(mx, s[mi][nj][r]);
#pragma unroll
        for (int off = 1; off < 16; off <<= 1) mx = fmaxf(mx, __shfl_xor(mx, off, 64));
        float sum = 0.f;
#pragma unroll
        for (int nj = 0; nj < 4; nj++) {
          const float e = __expf(s[mi][nj][r] - mx);
          s[mi][nj][r] = e;
          sum += e;
        }
#pragma unroll
        for (int off = 1; off < 16; off <<= 1) sum += __shfl_xor(sum, off, 64);
        const float inv = 1.0f / sum;
#pragma unroll
        for (int nj = 0; nj < 4; nj++)
          U[PL_OFF + (mi * 16 + quad * 4 + r) * 68 + nj * 16 + lr] = (bf16)(s[mi][nj][r] * inv);
      }

    f32x4 o[4][2] = {};
#pragma unroll
    for (int kq = 0; kq < 2; kq++) {
      bf16x8 pa[4], vb[2];
#pragma unroll
      for (int mi = 0; mi < 4; mi++)
        pa[mi] = lds8(&U[PL_OFF + (mi * 16 + lr) * 68 + kq * 32 + quad * 8]);
#pragma unroll
      for (int ni = 0; ni < 2; ni++)
        vb[ni] = lds8(&U[VT_OFF + (ni * 16 + lr) * 68 + kq * 32 + quad * 8]);
#pragma unroll
      for (int mi = 0; mi < 4; mi++)
#pragma unroll
        for (int ni = 0; ni < 2; ni++) o[mi][ni] = MFMA16(pa[mi], vb[ni], o[mi][ni]);
    }

#pragma unroll
    for (int mi = 0; mi < 4; mi++)
#pragma unroll
      for (int ni = 0; ni < 2; ni++)
#pragma unroll
        for (int r = 0; r < 4; r++) {
          const int t = mi * 16 + quad * 4 + r;
          const size_t row = (size_t)(base + (t >> 3) * 256 + (t & 7));
          out[row * 256 + h * 32 + ni * 16 + lr] = o[mi][ni][r];
        }
  }
}

__global__ __launch_bounds__(256) void proj_inplace(
    float* io, const float* __restrict__ W, const float* __restrict__ bias) {
  const int tid = threadIdx.x;
  const int wave = tid >> 6, lane = tid & 63;
  const int lr = lane & 15, quad = lane >> 4;
  const int row0 = blockIdx.x * 128 + (wave >> 1) * 64;
  const int col0 = (wave & 1) * 128;

  f32x4 acc[4][8] = {};
#pragma unroll
  for (int kk = 0; kk < 256; kk += 32) {
    bf16x8 a[4], b[8];
#pragma unroll
    for (int mi = 0; mi < 4; mi++)
      a[mi] = cvt8(io + (size_t)(row0 + mi * 16 + lr) * 256 + kk + quad * 8);
#pragma unroll
    for (int nj = 0; nj < 8; nj++)
      b[nj] = cvt8(W + (size_t)(col0 + nj * 16 + lr) * 256 + kk + quad * 8);
#pragma unroll
    for (int mi = 0; mi < 4; mi++)
#pragma unroll
      for (int nj = 0; nj < 8; nj++) acc[mi][nj] = MFMA16(a[mi], b[nj], acc[mi][nj]);
  }
  __syncthreads();
#pragma unroll
  for (int mi = 0; mi < 4; mi++)
#pragma unroll
    for (int nj = 0; nj < 8; nj++) {
      const int col = col0 + nj * 16 + lr;
      const float bv = bias[col];
#pragma unroll
      for (int r = 0; r < 4; r++) {
        const int row = row0 + mi * 16 + quad * 4 + r;
        io[(size_t)row * 256 + col] = acc[mi][nj][r] + bv;
      }
    }
}

extern "C" void kernel_launch(void* const* d_in, const int* in_sizes, int n_in,
                              void* d_out, int out_size, void* d_ws, size_t ws_size,
                              hipStream_t stream) {
  const float* x = (const float*)d_in[0];
  // d_in[1]=h, d_in[2]=w (fixed 256)
  const float* wqkv_w = (const float*)d_in[3];
  const float* wqkv_b = (const float*)d_in[4];
  const float* wp_w = (const float*)d_in[5];
  const float* wp_b = (const float*)d_in[6];
  const float* bias_table = (const float*)d_in[7];
  float* out = (float*)d_out;

  const size_t W_ELEMS = 196608 + 65536;                 // wqkv + wp bf16 elems
  const size_t NEED = W_ELEMS * 2 + (size_t)131072 * 256 * 2;  // 67,633,152 B

  if (ws_size >= NEED) {
    bf16* wbf = (bf16*)d_ws;                 // [0,196608) wqkv, [196608,262144) wp
    bf16* yb = wbf + W_ELEMS;                // y bf16 [131072][256]
    cvt_weights<<<256, 256, 0, stream>>>(wqkv_w, wp_w, wbf);
    fused_qkv_attn_v2<<<2048, 256, 0, stream>>>(x, wbf, wqkv_b, bias_table, yb);
    proj_v2<<<2048, 256, 0, stream>>>(yb, wbf + 196608, wp_b, out);
  } else {
    fused_qkv_attn<<<2048, 256, 0, stream>>>(x, wqkv_w, wqkv_b, bias_table, out);
    proj_inplace<<<1024, 256, 0, stream>>>(out, wp_w, wp_b);
  }
}

// Round 2
// 630.299 us; speedup vs baseline: 1.3752x; 1.3752x over previous
//
#include <hip/hip_runtime.h>
#include <hip/hip_bf16.h>

// SpatialWindowSelfAttention — MI355X gfx950.
// v3: ONE fused kernel (QKV proj + window attn + output proj), 3 barriers,
// 3 blocks/CU (52.2KB LDS, ~150 VGPR true pressure under the 168 cap),
// weights pre-permuted to MFMA-fragment order in ws (1KB coalesced wave loads).
// All transposes (qf/kf/pa) via the v2-verified cross-quad pack2+shfl transform.
// Fallback path (ws too small): previous verified two-kernel version.

typedef __bf16 bf16;
typedef bf16 bf16x2 __attribute__((ext_vector_type(2)));
typedef bf16 bf16x4 __attribute__((ext_vector_type(4)));
typedef bf16 bf16x8 __attribute__((ext_vector_type(8)));
typedef float f32x4 __attribute__((ext_vector_type(4)));
typedef int i32x4 __attribute__((ext_vector_type(4)));

#define MFMA16(a, b, c) __builtin_amdgcn_mfma_f32_16x16x32_bf16(a, b, c, 0, 0, 0)

__device__ __forceinline__ bf16x8 cvt8(const float* p) {  // 32B-aligned f32 -> bf16x8
  f32x4 lo = *(const f32x4*)p;
  f32x4 hi = *(const f32x4*)(p + 4);
  bf16x8 r;
#pragma unroll
  for (int j = 0; j < 4; j++) { r[j] = (bf16)lo[j]; r[j + 4] = (bf16)hi[j]; }
  return r;
}
__device__ __forceinline__ bf16x8 lds8(const bf16* p) {  // 8B-aligned LDS pair
  bf16x4 lo = *(const bf16x4*)p;
  bf16x4 hi = *(const bf16x4*)(p + 4);
  return __builtin_shufflevector(lo, hi, 0, 1, 2, 3, 4, 5, 6, 7);
}
__device__ __forceinline__ int pack2(float a, float b) {  // 2 f32 -> bf16x2 dword
  bf16x2 t; t[0] = (bf16)a; t[1] = (bf16)b;
  return __builtin_bit_cast(int, t);
}

// ======================= FAST PATH (v3) =======================

// K0: permute+convert weights into MFMA-fragment order.
// wqf entry (ct,kb,lane) @ dst[((ct*8+kb)*64+lane)*8] = wq[ct*16+(lane&15)][kb*32+(lane>>4)*8 ..+7]
// ct in [0,48) for wqkv (rows 0..767); wpf same with ct in [0,16) at dst+196608.
__global__ __launch_bounds__(256) void cvt_weights_v3(
    const float* __restrict__ wq, const float* __restrict__ wp, bf16* __restrict__ dst) {
  const int did = blockIdx.x * 256 + threadIdx.x;  // [0, 32768)
  const float* src;
  bf16* o;
  if (did < 24576) {
    const int ct = did >> 9, rem = did & 511, kb = rem >> 6, ln = rem & 63;
    src = wq + (size_t)(ct * 16 + (ln & 15)) * 256 + kb * 32 + (ln >> 4) * 8;
    o = dst + (size_t)did * 8;
  } else {
    const int d2 = did - 24576;
    const int ct = d2 >> 9, rem = d2 & 511, kb = rem >> 6, ln = rem & 63;
    src = wp + (size_t)(ct * 16 + (ln & 15)) * 256 + kb * 32 + (ln >> 4) * 8;
    o = dst + 196608 + (size_t)d2 * 8;
  }
  *(bf16x8*)o = cvt8(src);
}

// Per-head attention: QKV (W-major: m=ch on quad*4+r, n=tok on lr) -> attn -> y packed to ob[16].
__device__ __forceinline__ void attn_head(
    const int h, const int lane, const int lr, const int quad,
    const bf16 (*__restrict__ xs)[264], bf16* __restrict__ U,
    const bf16* __restrict__ wqf, const float* __restrict__ wqkv_b,
    const float* __restrict__ bias_table, int* __restrict__ ob) {
  const f32x4 zero = {0.f, 0.f, 0.f, 0.f};
  const float scale = 0.17677669529663687f;  // 1/sqrt(32)
  const int L0 = ((quad & 1) << 5) | lr, L1 = L0 + 16;
  const bool hiq = quad >= 2;

  // ---- pass 1: Q (mi 0..1) and K (mi 2..3) tiles, K-dim = 256 in one sweep ----
  f32x4 acc[4][4] = {};
  const int ctq = 2 * h, ctk = 16 + 2 * h;
#pragma unroll
  for (int kb = 0; kb < 8; ++kb) {
    bf16x8 b[4];
#pragma unroll
    for (int nj = 0; nj < 4; ++nj) b[nj] = lds8(&xs[nj * 16 + lr][kb * 32 + quad * 8]);
#pragma unroll
    for (int mi = 0; mi < 4; ++mi) {
      const int ct = (mi < 2) ? (ctq + mi) : (ctk + mi - 2);
      const bf16x8 a = *(const bf16x8*)&wqf[(size_t)((ct * 8 + kb) * 64 + lane) * 8];
#pragma unroll
      for (int nj = 0; nj < 4; ++nj) acc[mi][nj] = MFMA16(a, b[nj], acc[mi][nj]);
    }
  }
  // bias (ch = cb + quad*4 + r)
#pragma unroll
  for (int mi = 0; mi < 4; ++mi) {
    const int cb = (mi < 2) ? (h * 32 + mi * 16) : (256 + h * 32 + (mi - 2) * 16);
    const f32x4 bb = *(const f32x4*)&wqkv_b[cb + quad * 4];
#pragma unroll
    for (int nj = 0; nj < 4; ++nj)
#pragma unroll
      for (int r = 0; r < 4; ++r) acc[mi][nj][r] += bb[r];
  }
  // ---- build qf (B-frag: n=qtok on lr, k=d on quad*8+j) and kf (A-frag, same map) ----
  bf16x8 qf[4], kf[4];
  {
    int pA[2][4], pB[2][4];
#pragma unroll
    for (int mi = 0; mi < 2; ++mi)
#pragma unroll
      for (int nj = 0; nj < 4; ++nj) {
        pA[mi][nj] = pack2(acc[mi][nj][0], acc[mi][nj][1]);
        pB[mi][nj] = pack2(acc[mi][nj][2], acc[mi][nj][3]);
      }
#pragma unroll
    for (int t = 0; t < 4; ++t) {
      const int a0 = __shfl(pA[0][t], L0, 64), a1 = __shfl(pA[1][t], L0, 64);
      const int b0 = __shfl(pB[0][t], L0, 64), b1 = __shfl(pB[1][t], L0, 64);
      const int a0h = __shfl(pA[0][t], L1, 64), a1h = __shfl(pA[1][t], L1, 64);
      const int b0h = __shfl(pB[0][t], L1, 64), b1h = __shfl(pB[1][t], L1, 64);
      const i32x4 w = {hiq ? a1 : a0, hiq ? b1 : b0, hiq ? a1h : a0h, hiq ? b1h : b0h};
      qf[t] = __builtin_bit_cast(bf16x8, w);
    }
#pragma unroll
    for (int mi = 0; mi < 2; ++mi)
#pragma unroll
      for (int nj = 0; nj < 4; ++nj) {
        pA[mi][nj] = pack2(acc[2 + mi][nj][0], acc[2 + mi][nj][1]);
        pB[mi][nj] = pack2(acc[2 + mi][nj][2], acc[2 + mi][nj][3]);
      }
#pragma unroll
    for (int t = 0; t < 4; ++t) {
      const int a0 = __shfl(pA[0][t], L0, 64), a1 = __shfl(pA[1][t], L0, 64);
      const int b0 = __shfl(pB[0][t], L0, 64), b1 = __shfl(pB[1][t], L0, 64);
      const int a0h = __shfl(pA[0][t], L1, 64), a1h = __shfl(pA[1][t], L1, 64);
      const int b0h = __shfl(pB[0][t], L1, 64), b1h = __shfl(pB[1][t], L1, 64);
      const i32x4 w = {hiq ? a1 : a0, hiq ? b1 : b0, hiq ? a1h : a0h, hiq ? b1h : b0h};
      kf[t] = __builtin_bit_cast(bf16x8, w);
    }
  }
  // ---- S^T = K Q^T : ktok = kt*16+quad*4+r, qtok = qt*16+lr ----
  f32x4 s[4][4];
#pragma unroll
  for (int kt = 0; kt < 4; ++kt)
#pragma unroll
    for (int qt = 0; qt < 4; ++qt) s[kt][qt] = MFMA16(kf[kt], qf[qt], zero);
#pragma unroll
  for (int kt = 0; kt < 4; ++kt)
#pragma unroll
    for (int r = 0; r < 4; ++r) {
      const int ktok = kt * 16 + quad * 4 + r;
#pragma unroll
      for (int qt = 0; qt < 4; ++qt) {
        const int qtok = qt * 16 + lr;
        const int idx = ((qtok >> 3) - (ktok >> 3) + 7) * 15 + (qtok & 7) - (ktok & 7) + 7;
        s[kt][qt][r] = s[kt][qt][r] * scale + bias_table[idx * 8 + h];
      }
    }
  // ---- softmax over k (16 in-lane + 2 cross-quad shuffles per q) ----
  float inv[4];
#pragma unroll
  for (int qt = 0; qt < 4; ++qt) {
    float mx = -1e30f;
#pragma unroll
    for (int kt = 0; kt < 4; ++kt)
#pragma unroll
      for (int r = 0; r < 4; ++r) mx = fmaxf(mx, s[kt][qt][r]);
    mx = fmaxf(mx, __shfl_xor(mx, 16, 64));
    mx = fmaxf(mx, __shfl_xor(mx, 32, 64));
    float sum = 0.f;
#pragma unroll
    for (int kt = 0; kt < 4; ++kt)
#pragma unroll
      for (int r = 0; r < 4; ++r) {
        const float e = __expf(s[kt][qt][r] - mx);
        s[kt][qt][r] = e;
        sum += e;
      }
    sum += __shfl_xor(sum, 16, 64);
    sum += __shfl_xor(sum, 32, 64);
    inv[qt] = 1.0f / sum;
  }
  // ---- pa (A-frag: m=qtok on lr, k=ktok on quad*8+j), same shuffle transform ----
  bf16x8 pa[4][2];
  {
    int pA[4][4], pB[4][4];
#pragma unroll
    for (int kt = 0; kt < 4; ++kt)
#pragma unroll
      for (int qt = 0; qt < 4; ++qt) {
        pA[kt][qt] = pack2(s[kt][qt][0] * inv[qt], s[kt][qt][1] * inv[qt]);
        pB[kt][qt] = pack2(s[kt][qt][2] * inv[qt], s[kt][qt][3] * inv[qt]);
      }
#pragma unroll
    for (int kq = 0; kq < 2; ++kq)
#pragma unroll
      for (int mt = 0; mt < 4; ++mt) {
        const int x0 = __shfl(pA[kq * 2][mt], L0, 64), x1 = __shfl(pA[kq * 2 + 1][mt], L0, 64);
        const int y0 = __shfl(pB[kq * 2][mt], L0, 64), y1 = __shfl(pB[kq * 2 + 1][mt], L0, 64);
        const int x0h = __shfl(pA[kq * 2][mt], L1, 64), x1h = __shfl(pA[kq * 2 + 1][mt], L1, 64);
        const int y0h = __shfl(pB[kq * 2][mt], L1, 64), y1h = __shfl(pB[kq * 2 + 1][mt], L1, 64);
        const i32x4 w = {hiq ? x1 : x0, hiq ? y1 : y0, hiq ? x1h : x0h, hiq ? y1h : y0h};
        pa[mt][kq] = __builtin_bit_cast(bf16x8, w);
      }
  }
  // ---- pass 2: V (2 ch-tiles) ----
  f32x4 av[2][4] = {};
  const int ctv = 32 + 2 * h;
#pragma unroll
  for (int kb = 0; kb < 8; ++kb) {
    bf16x8 b[4];
#pragma unroll
    for (int nj = 0; nj < 4; ++nj) b[nj] = lds8(&xs[nj * 16 + lr][kb * 32 + quad * 8]);
#pragma unroll
    for (int mi = 0; mi < 2; ++mi) {
      const bf16x8 a = *(const bf16x8*)&wqf[(size_t)(((ctv + mi) * 8 + kb) * 64 + lane) * 8];
#pragma unroll
      for (int nj = 0; nj < 4; ++nj) av[mi][nj] = MFMA16(a, b[nj], av[mi][nj]);
    }
  }
  // V bias + transpose into Vt[d][tok] (stride 72) in per-wave LDS
#pragma unroll
  for (int mi = 0; mi < 2; ++mi) {
    const f32x4 bb = *(const f32x4*)&wqkv_b[512 + h * 32 + mi * 16 + quad * 4];
#pragma unroll
    for (int nj = 0; nj < 4; ++nj)
#pragma unroll
      for (int r = 0; r < 4; ++r)
        U[(mi * 16 + quad * 4 + r) * 72 + nj * 16 + lr] = (bf16)(av[mi][nj][r] + bb[r]);
  }
  // ---- O = P @ V ----
  f32x4 o[4][2] = {};
#pragma unroll
  for (int kq = 0; kq < 2; ++kq) {
    bf16x8 vb[2];
#pragma unroll
    for (int ni = 0; ni < 2; ++ni) vb[ni] = lds8(&U[(ni * 16 + lr) * 72 + kq * 32 + quad * 8]);
#pragma unroll
    for (int mt = 0; mt < 4; ++mt)
#pragma unroll
      for (int ni = 0; ni < 2; ++ni) o[mt][ni] = MFMA16(pa[mt][kq], vb[ni], o[mt][ni]);
  }
  // pack y (bf16 pairs along r) into ob[16]
#pragma unroll
  for (int mt = 0; mt < 4; ++mt)
#pragma unroll
    for (int ni = 0; ni < 2; ++ni)
#pragma unroll
      for (int w2 = 0; w2 < 2; ++w2)
        ob[(mt * 2 + ni) * 2 + w2] = pack2(o[mt][ni][2 * w2], o[mt][ni][2 * w2 + 1]);
}

// Fused kernel: stage x -> per-wave heads -> y into xs -> output projection.
__global__ __launch_bounds__(256, 3) void swin_fused_v3(
    const float* __restrict__ x, const bf16* __restrict__ wqf,
    const float* __restrict__ wqkv_b, const float* __restrict__ bias_table,
    const bf16* __restrict__ wpf, const float* __restrict__ wp_b,
    float* __restrict__ out) {
  __shared__ __align__(16) bf16 xs[64][264];   // x window, later reused as y
  __shared__ __align__(16) bf16 uni[4][2304];  // per-wave Vt[32][72]

  const int tid = threadIdx.x;
  const int wave = tid >> 6, lane = tid & 63;
  const int lr = lane & 15, quad = lane >> 4;
  const int win = blockIdx.x;  // [0,2048)
  const int batch = win >> 10, wy = (win >> 5) & 31, wx = win & 31;
  const int base = batch * 65536 + wy * 2048 + wx * 8;
  bf16* const U = &uni[wave][0];

  // ---- stage full x window [64 tok][256 ch] f32 -> bf16 ----
  {
    const int tok = tid >> 2, cg = (tid & 3) * 64;
    const float* xp = x + (size_t)(base + ((tok >> 3) << 8) + (tok & 7)) * 256 + cg;
#pragma unroll
    for (int g = 0; g < 8; ++g) *(bf16x8*)&xs[tok][cg + g * 8] = cvt8(xp + g * 8);
  }
  __syncthreads();  // barrier 1

  int ob0[16], ob1[16];
  attn_head(wave * 2 + 0, lane, lr, quad, (const bf16(*)[264])xs, U, wqf, wqkv_b, bias_table, ob0);
  attn_head(wave * 2 + 1, lane, lr, quad, (const bf16(*)[264])xs, U, wqf, wqkv_b, bias_table, ob1);

  __syncthreads();  // barrier 2: all waves done reading x from xs
  // ---- write y (bf16) into xs[tok][ch]; wave covers its 2 heads' 64 channels ----
#pragma unroll
  for (int rep = 0; rep < 2; ++rep) {
    const int* ob = rep ? ob1 : ob0;
    const int hh = wave * 2 + rep;
#pragma unroll
    for (int mt = 0; mt < 4; ++mt)
#pragma unroll
      for (int ni = 0; ni < 2; ++ni)
#pragma unroll
        for (int w2 = 0; w2 < 2; ++w2) {
          const bf16x2 t = __builtin_bit_cast(bf16x2, ob[(mt * 2 + ni) * 2 + w2]);
#pragma unroll
          for (int e = 0; e < 2; ++e)
            xs[mt * 16 + quad * 4 + w2 * 2 + e][hh * 32 + ni * 16 + lr] = t[e];
        }
  }
  __syncthreads();  // barrier 3: y complete
  // ---- output projection: out[64 tok][256] = y @ wp^T + b; wave owns 64 cols ----
  f32x4 ap[4][4] = {};
#pragma unroll
  for (int kb = 0; kb < 8; ++kb) {
    bf16x8 a[4], b[4];
#pragma unroll
    for (int mt = 0; mt < 4; ++mt) a[mt] = lds8(&xs[mt * 16 + lr][kb * 32 + quad * 8]);
#pragma unroll
    for (int nt = 0; nt < 4; ++nt)
      b[nt] = *(const bf16x8*)&wpf[(size_t)(((wave * 4 + nt) * 8 + kb) * 64 + lane) * 8];
#pragma unroll
    for (int mt = 0; mt < 4; ++mt)
#pragma unroll
      for (int nt = 0; nt < 4; ++nt) ap[mt][nt] = MFMA16(a[mt], b[nt], ap[mt][nt]);
  }
#pragma unroll
  for (int nt = 0; nt < 4; ++nt) {
    const int col = (wave * 4 + nt) * 16 + lr;
    const float bv = wp_b[col];
#pragma unroll
    for (int mt = 0; mt < 4; ++mt)
#pragma unroll
      for (int r = 0; r < 4; ++r) {
        const int t = mt * 16 + quad * 4 + r;
        const size_t grow = (size_t)(base + ((t >> 3) << 8) + (t & 7));
        out[grow * 256 + col] = ap[mt][nt][r] + bv;
      }
  }
}

// ======================= FALLBACK PATH (previous verified kernels) =======================

#define QS_OFF 0
#define KS_OFF 2304
#define VT_OFF 4608
#define PL_OFF 0
#define UNI_SZ 6784

__global__ __launch_bounds__(256) void fused_qkv_attn(
    const float* __restrict__ x, const float* __restrict__ wqkv_w,
    const float* __restrict__ wqkv_b, const float* __restrict__ bias_table,
    float* __restrict__ out) {
  __shared__ bf16 xs[64][72];
  __shared__ bf16 uni[4][UNI_SZ];

  const int tid = threadIdx.x;
  const int wave = tid >> 6, lane = tid & 63;
  const int lr = lane & 15, quad = lane >> 4;
  const int win = blockIdx.x;
  const int batch = win >> 10, wy = (win >> 5) & 31, wx = win & 31;
  const int base = batch * 65536 + wy * 2048 + wx * 8;
  bf16* const U = &uni[wave][0];

  const f32x4 zero = {0.f, 0.f, 0.f, 0.f};
  const float scale = 0.17677669529663687f;

  for (int rep = 0; rep < 2; rep++) {
    const int h = wave * 2 + rep;
    const int cb[6] = {h * 32,       h * 32 + 16,
                       256 + h * 32, 256 + h * 32 + 16,
                       512 + h * 32, 512 + h * 32 + 16};

    f32x4 acc[4][6] = {};
    for (int kc = 0; kc < 4; kc++) {
      __syncthreads();
      {
        const int t = tid >> 2, c0 = (tid & 3) * 16;
        const float* xp = x + (size_t)(base + (t >> 3) * 256 + (t & 7)) * 256 + kc * 64 + c0;
        *(bf16x8*)&xs[t][c0] = cvt8(xp);
        *(bf16x8*)&xs[t][c0 + 8] = cvt8(xp + 8);
      }
      __syncthreads();
#pragma unroll
      for (int k2 = 0; k2 < 64; k2 += 32) {
        bf16x8 a[4], b[6];
#pragma unroll
        for (int mi = 0; mi < 4; mi++) a[mi] = lds8(&xs[mi * 16 + lr][k2 + quad * 8]);
#pragma unroll
        for (int nj = 0; nj < 6; nj++)
          b[nj] = cvt8(wqkv_w + (size_t)(cb[nj] + lr) * 256 + kc * 64 + k2 + quad * 8);
#pragma unroll
        for (int mi = 0; mi < 4; mi++)
#pragma unroll
          for (int nj = 0; nj < 6; nj++) acc[mi][nj] = MFMA16(a[mi], b[nj], acc[mi][nj]);
      }
    }

#pragma unroll
    for (int nj = 0; nj < 6; nj++) {
      const float bv = wqkv_b[cb[nj] + lr];
#pragma unroll
      for (int mi = 0; mi < 4; mi++)
#pragma unroll
        for (int r = 0; r < 4; r++) {
          const int tok = mi * 16 + quad * 4 + r;
          const float v = acc[mi][nj][r] + bv;
          if (nj < 2)      U[QS_OFF + tok * 36 + nj * 16 + lr] = (bf16)v;
          else if (nj < 4) U[KS_OFF + tok * 36 + (nj - 2) * 16 + lr] = (bf16)v;
          else             U[VT_OFF + ((nj - 4) * 16 + lr) * 68 + tok] = (bf16)v;
        }
    }

    bf16x8 qf[4], kf[4];
#pragma unroll
    for (int i = 0; i < 4; i++) {
      qf[i] = lds8(&U[QS_OFF + (i * 16 + lr) * 36 + quad * 8]);
      kf[i] = lds8(&U[KS_OFF + (i * 16 + lr) * 36 + quad * 8]);
    }
    f32x4 s[4][4];
#pragma unroll
    for (int mi = 0; mi < 4; mi++)
#pragma unroll
      for (int nj = 0; nj < 4; nj++) s[mi][nj] = MFMA16(qf[mi], kf[nj], zero);

#pragma unroll
    for (int mi = 0; mi < 4; mi++)
#pragma unroll
      for (int nj = 0; nj < 4; nj++)
#pragma unroll
        for (int r = 0; r < 4; r++) {
          const int qt = mi * 16 + quad * 4 + r;
          const int kt = nj * 16 + lr;
          const int idx = ((qt >> 3) - (kt >> 3) + 7) * 15 + ((qt & 7) - (kt & 7) + 7);
          s[mi][nj][r] = s[mi][nj][r] * scale + bias_table[idx * 8 + h];
        }

#pragma unroll
    for (int mi = 0; mi < 4; mi++)
#pragma unroll
      for (int r = 0; r < 4; r++) {
        float mx = -1e30f;
#pragma unroll
        for (int nj = 0; nj < 4; nj++) mx = fmaxf(mx, s[mi][nj][r]);
#pragma unroll
        for (int off = 1; off < 16; off <<= 1) mx = fmaxf(mx, __shfl_xor(mx, off, 64));
        float sum = 0.f;
#pragma unroll
        for (int nj = 0; nj < 4; nj++) {
          const float e = __expf(s[mi][nj][r] - mx);
          s[mi][nj][r] = e;
          sum += e;
        }
#pragma unroll
        for (int off = 1; off < 16; off <<= 1) sum += __shfl_xor(sum, off, 64);
        const float inv = 1.0f / sum;
#pragma unroll
        for (int nj = 0; nj < 4; nj++)
          U[PL_OFF + (mi * 16 + quad * 4 + r) * 68 + nj * 16 + lr] = (bf16)(s[mi][nj][r] * inv);
      }

    f32x4 o[4][2] = {};
#pragma unroll
    for (int kq = 0; kq < 2; kq++) {
      bf16x8 pa[4], vb[2];
#pragma unroll
      for (int mi = 0; mi < 4; mi++)
        pa[mi] = lds8(&U[PL_OFF + (mi * 16 + lr) * 68 + kq * 32 + quad * 8]);
#pragma unroll
      for (int ni = 0; ni < 2; ni++)
        vb[ni] = lds8(&U[VT_OFF + (ni * 16 + lr) * 68 + kq * 32 + quad * 8]);
#pragma unroll
      for (int mi = 0; mi < 4; mi++)
#pragma unroll
        for (int ni = 0; ni < 2; ni++) o[mi][ni] = MFMA16(pa[mi], vb[ni], o[mi][ni]);
    }

#pragma unroll
    for (int mi = 0; mi < 4; mi++)
#pragma unroll
      for (int ni = 0; ni < 2; ni++)
#pragma unroll
        for (int r = 0; r < 4; r++) {
          const int t = mi * 16 + quad * 4 + r;
          const size_t row = (size_t)(base + (t >> 3) * 256 + (t & 7));
          out[row * 256 + h * 32 + ni * 16 + lr] = o[mi][ni][r];
        }
  }
}

__global__ __launch_bounds__(256) void proj_inplace(
    float* io, const float* __restrict__ W, const float* __restrict__ bias) {
  const int tid = threadIdx.x;
  const int wave = tid >> 6, lane = tid & 63;
  const int lr = lane & 15, quad = lane >> 4;
  const int row0 = blockIdx.x * 128 + (wave >> 1) * 64;
  const int col0 = (wave & 1) * 128;

  f32x4 acc[4][8] = {};
#pragma unroll
  for (int kk = 0; kk < 256; kk += 32) {
    bf16x8 a[4], b[8];
#pragma unroll
    for (int mi = 0; mi < 4; mi++)
      a[mi] = cvt8(io + (size_t)(row0 + mi * 16 + lr) * 256 + kk + quad * 8);
#pragma unroll
    for (int nj = 0; nj < 8; nj++)
      b[nj] = cvt8(W + (size_t)(col0 + nj * 16 + lr) * 256 + kk + quad * 8);
#pragma unroll
    for (int mi = 0; mi < 4; mi++)
#pragma unroll
      for (int nj = 0; nj < 8; nj++) acc[mi][nj] = MFMA16(a[mi], b[nj], acc[mi][nj]);
  }
  __syncthreads();
#pragma unroll
  for (int mi = 0; mi < 4; mi++)
#pragma unroll
    for (int nj = 0; nj < 8; nj++) {
      const int col = col0 + nj * 16 + lr;
      const float bv = bias[col];
#pragma unroll
      for (int r = 0; r < 4; r++) {
        const int row = row0 + mi * 16 + quad * 4 + r;
        io[(size_t)row * 256 + col] = acc[mi][nj][r] + bv;
      }
    }
}

extern "C" void kernel_launch(void* const* d_in, const int* in_sizes, int n_in,
                              void* d_out, int out_size, void* d_ws, size_t ws_size,
                              hipStream_t stream) {
  const float* x = (const float*)d_in[0];
  // d_in[1]=h, d_in[2]=w (fixed 256)
  const float* wqkv_w = (const float*)d_in[3];
  const float* wqkv_b = (const float*)d_in[4];
  const float* wp_w = (const float*)d_in[5];
  const float* wp_b = (const float*)d_in[6];
  const float* bias_table = (const float*)d_in[7];
  float* out = (float*)d_out;

  const size_t NEED = (size_t)(196608 + 65536) * sizeof(bf16);  // 524,288 B

  if (ws_size >= NEED) {
    bf16* wbf = (bf16*)d_ws;  // [0,196608) wqkv frag-order, [196608,262144) wp frag-order
    cvt_weights_v3<<<128, 256, 0, stream>>>(wqkv_w, wp_w, wbf);
    swin_fused_v3<<<2048, 256, 0, stream>>>(x, wbf, wqkv_b, bias_table,
                                            wbf + 196608, wp_b, out);
  } else {
    fused_qkv_attn<<<2048, 256, 0, stream>>>(x, wqkv_w, wqkv_b, bias_table, out);
    proj_inplace<<<1024, 256, 0, stream>>>(out, wp_w, wp_b);
  }
}

// Round 4
// 468.864 us; speedup vs baseline: 1.8487x; 1.3443x over previous
//
#include <hip/hip_runtime.h>
#include <hip/hip_bf16.h>

// SpatialWindowSelfAttention — MI355X gfx950.
// v4 = v3 structure (ONE fused kernel: QKV proj + window attn + output proj,
// 3 barriers, weights pre-permuted to MFMA-fragment order in ws) with the
// register-spill fix: plain __launch_bounds__(256). R2's (256,3) split the
// 168-reg budget into 84 VGPR + 84 AGPR -> ~1GB scratch traffic (WRITE 735MB
// vs 134MB ideal). R0's launch_bounds(256) config (208 VGPR) had ZERO scratch.
// R3 bench was an infra failure (container died) — identical resubmission.
// Fallback path (ws too small): previous verified two-kernel version.

typedef __bf16 bf16;
typedef bf16 bf16x2 __attribute__((ext_vector_type(2)));
typedef bf16 bf16x4 __attribute__((ext_vector_type(4)));
typedef bf16 bf16x8 __attribute__((ext_vector_type(8)));
typedef float f32x4 __attribute__((ext_vector_type(4)));
typedef int i32x4 __attribute__((ext_vector_type(4)));

#define MFMA16(a, b, c) __builtin_amdgcn_mfma_f32_16x16x32_bf16(a, b, c, 0, 0, 0)

__device__ __forceinline__ bf16x8 cvt8(const float* p) {  // 32B-aligned f32 -> bf16x8
  f32x4 lo = *(const f32x4*)p;
  f32x4 hi = *(const f32x4*)(p + 4);
  bf16x8 r;
#pragma unroll
  for (int j = 0; j < 4; j++) { r[j] = (bf16)lo[j]; r[j + 4] = (bf16)hi[j]; }
  return r;
}
__device__ __forceinline__ bf16x8 lds8(const bf16* p) {  // 8B-aligned LDS pair
  bf16x4 lo = *(const bf16x4*)p;
  bf16x4 hi = *(const bf16x4*)(p + 4);
  return __builtin_shufflevector(lo, hi, 0, 1, 2, 3, 4, 5, 6, 7);
}
__device__ __forceinline__ int pack2(float a, float b) {  // 2 f32 -> bf16x2 dword
  bf16x2 t; t[0] = (bf16)a; t[1] = (bf16)b;
  return __builtin_bit_cast(int, t);
}

// ======================= FAST PATH (v4) =======================

// K0: permute+convert weights into MFMA-fragment order.
// wqf entry (ct,kb,lane) @ dst[((ct*8+kb)*64+lane)*8] = wq[ct*16+(lane&15)][kb*32+(lane>>4)*8 ..+7]
// ct in [0,48) for wqkv (rows 0..767); wpf same with ct in [0,16) at dst+196608.
__global__ __launch_bounds__(256) void cvt_weights_v3(
    const float* __restrict__ wq, const float* __restrict__ wp, bf16* __restrict__ dst) {
  const int did = blockIdx.x * 256 + threadIdx.x;  // [0, 32768)
  const float* src;
  bf16* o;
  if (did < 24576) {
    const int ct = did >> 9, rem = did & 511, kb = rem >> 6, ln = rem & 63;
    src = wq + (size_t)(ct * 16 + (ln & 15)) * 256 + kb * 32 + (ln >> 4) * 8;
    o = dst + (size_t)did * 8;
  } else {
    const int d2 = did - 24576;
    const int ct = d2 >> 9, rem = d2 & 511, kb = rem >> 6, ln = rem & 63;
    src = wp + (size_t)(ct * 16 + (ln & 15)) * 256 + kb * 32 + (ln >> 4) * 8;
    o = dst + 196608 + (size_t)d2 * 8;
  }
  *(bf16x8*)o = cvt8(src);
}

// Per-head attention: QKV (W-major: m=ch on quad*4+r, n=tok on lr) -> attn -> y packed to ob[16].
__device__ __forceinline__ void attn_head(
    const int h, const int lane, const int lr, const int quad,
    const bf16 (*__restrict__ xs)[264], bf16* __restrict__ U,
    const bf16* __restrict__ wqf, const float* __restrict__ wqkv_b,
    const float* __restrict__ bias_table, int* __restrict__ ob) {
  const f32x4 zero = {0.f, 0.f, 0.f, 0.f};
  const float scale = 0.17677669529663687f;  // 1/sqrt(32)
  const int L0 = ((quad & 1) << 5) | lr, L1 = L0 + 16;
  const bool hiq = quad >= 2;

  // ---- pass 1: Q (mi 0..1) and K (mi 2..3) tiles, K-dim = 256 in one sweep ----
  f32x4 acc[4][4] = {};
  const int ctq = 2 * h, ctk = 16 + 2 * h;
#pragma unroll
  for (int kb = 0; kb < 8; ++kb) {
    bf16x8 b[4];
#pragma unroll
    for (int nj = 0; nj < 4; ++nj) b[nj] = lds8(&xs[nj * 16 + lr][kb * 32 + quad * 8]);
#pragma unroll
    for (int mi = 0; mi < 4; ++mi) {
      const int ct = (mi < 2) ? (ctq + mi) : (ctk + mi - 2);
      const bf16x8 a = *(const bf16x8*)&wqf[(size_t)((ct * 8 + kb) * 64 + lane) * 8];
#pragma unroll
      for (int nj = 0; nj < 4; ++nj) acc[mi][nj] = MFMA16(a, b[nj], acc[mi][nj]);
    }
  }
  // bias (ch = cb + quad*4 + r)
#pragma unroll
  for (int mi = 0; mi < 4; ++mi) {
    const int cb = (mi < 2) ? (h * 32 + mi * 16) : (256 + h * 32 + (mi - 2) * 16);
    const f32x4 bb = *(const f32x4*)&wqkv_b[cb + quad * 4];
#pragma unroll
    for (int nj = 0; nj < 4; ++nj)
#pragma unroll
      for (int r = 0; r < 4; ++r) acc[mi][nj][r] += bb[r];
  }
  // ---- build qf (B-frag: n=qtok on lr, k=d on quad*8+j) and kf (A-frag, same map) ----
  bf16x8 qf[4], kf[4];
  {
    int pA[2][4], pB[2][4];
#pragma unroll
    for (int mi = 0; mi < 2; ++mi)
#pragma unroll
      for (int nj = 0; nj < 4; ++nj) {
        pA[mi][nj] = pack2(acc[mi][nj][0], acc[mi][nj][1]);
        pB[mi][nj] = pack2(acc[mi][nj][2], acc[mi][nj][3]);
      }
#pragma unroll
    for (int t = 0; t < 4; ++t) {
      const int a0 = __shfl(pA[0][t], L0, 64), a1 = __shfl(pA[1][t], L0, 64);
      const int b0 = __shfl(pB[0][t], L0, 64), b1 = __shfl(pB[1][t], L0, 64);
      const int a0h = __shfl(pA[0][t], L1, 64), a1h = __shfl(pA[1][t], L1, 64);
      const int b0h = __shfl(pB[0][t], L1, 64), b1h = __shfl(pB[1][t], L1, 64);
      const i32x4 w = {hiq ? a1 : a0, hiq ? b1 : b0, hiq ? a1h : a0h, hiq ? b1h : b0h};
      qf[t] = __builtin_bit_cast(bf16x8, w);
    }
#pragma unroll
    for (int mi = 0; mi < 2; ++mi)
#pragma unroll
      for (int nj = 0; nj < 4; ++nj) {
        pA[mi][nj] = pack2(acc[2 + mi][nj][0], acc[2 + mi][nj][1]);
        pB[mi][nj] = pack2(acc[2 + mi][nj][2], acc[2 + mi][nj][3]);
      }
#pragma unroll
    for (int t = 0; t < 4; ++t) {
      const int a0 = __shfl(pA[0][t], L0, 64), a1 = __shfl(pA[1][t], L0, 64);
      const int b0 = __shfl(pB[0][t], L0, 64), b1 = __shfl(pB[1][t], L0, 64);
      const int a0h = __shfl(pA[0][t], L1, 64), a1h = __shfl(pA[1][t], L1, 64);
      const int b0h = __shfl(pB[0][t], L1, 64), b1h = __shfl(pB[1][t], L1, 64);
      const i32x4 w = {hiq ? a1 : a0, hiq ? b1 : b0, hiq ? a1h : a0h, hiq ? b1h : b0h};
      kf[t] = __builtin_bit_cast(bf16x8, w);
    }
  }
  // ---- S^T = K Q^T : ktok = kt*16+quad*4+r, qtok = qt*16+lr ----
  f32x4 s[4][4];
#pragma unroll
  for (int kt = 0; kt < 4; ++kt)
#pragma unroll
    for (int qt = 0; qt < 4; ++qt) s[kt][qt] = MFMA16(kf[kt], qf[qt], zero);
#pragma unroll
  for (int kt = 0; kt < 4; ++kt)
#pragma unroll
    for (int r = 0; r < 4; ++r) {
      const int ktok = kt * 16 + quad * 4 + r;
#pragma unroll
      for (int qt = 0; qt < 4; ++qt) {
        const int qtok = qt * 16 + lr;
        const int idx = ((qtok >> 3) - (ktok >> 3) + 7) * 15 + (qtok & 7) - (ktok & 7) + 7;
        s[kt][qt][r] = s[kt][qt][r] * scale + bias_table[idx * 8 + h];
      }
    }
  // ---- softmax over k (16 in-lane + 2 cross-quad shuffles per q) ----
  float inv[4];
#pragma unroll
  for (int qt = 0; qt < 4; ++qt) {
    float mx = -1e30f;
#pragma unroll
    for (int kt = 0; kt < 4; ++kt)
#pragma unroll
      for (int r = 0; r < 4; ++r) mx = fmaxf(mx, s[kt][qt][r]);
    mx = fmaxf(mx, __shfl_xor(mx, 16, 64));
    mx = fmaxf(mx, __shfl_xor(mx, 32, 64));
    float sum = 0.f;
#pragma unroll
    for (int kt = 0; kt < 4; ++kt)
#pragma unroll
      for (int r = 0; r < 4; ++r) {
        const float e = __expf(s[kt][qt][r] - mx);
        s[kt][qt][r] = e;
        sum += e;
      }
    sum += __shfl_xor(sum, 16, 64);
    sum += __shfl_xor(sum, 32, 64);
    inv[qt] = 1.0f / sum;
  }
  // ---- pa (A-frag: m=qtok on lr, k=ktok on quad*8+j), same shuffle transform ----
  bf16x8 pa[4][2];
  {
    int pA[4][4], pB[4][4];
#pragma unroll
    for (int kt = 0; kt < 4; ++kt)
#pragma unroll
      for (int qt = 0; qt < 4; ++qt) {
        pA[kt][qt] = pack2(s[kt][qt][0] * inv[qt], s[kt][qt][1] * inv[qt]);
        pB[kt][qt] = pack2(s[kt][qt][2] * inv[qt], s[kt][qt][3] * inv[qt]);
      }
#pragma unroll
    for (int kq = 0; kq < 2; ++kq)
#pragma unroll
      for (int mt = 0; mt < 4; ++mt) {
        const int x0 = __shfl(pA[kq * 2][mt], L0, 64), x1 = __shfl(pA[kq * 2 + 1][mt], L0, 64);
        const int y0 = __shfl(pB[kq * 2][mt], L0, 64), y1 = __shfl(pB[kq * 2 + 1][mt], L0, 64);
        const int x0h = __shfl(pA[kq * 2][mt], L1, 64), x1h = __shfl(pA[kq * 2 + 1][mt], L1, 64);
        const int y0h = __shfl(pB[kq * 2][mt], L1, 64), y1h = __shfl(pB[kq * 2 + 1][mt], L1, 64);
        const i32x4 w = {hiq ? x1 : x0, hiq ? y1 : y0, hiq ? x1h : x0h, hiq ? y1h : y0h};
        pa[mt][kq] = __builtin_bit_cast(bf16x8, w);
      }
  }
  // ---- pass 2: V (2 ch-tiles) ----
  f32x4 av[2][4] = {};
  const int ctv = 32 + 2 * h;
#pragma unroll
  for (int kb = 0; kb < 8; ++kb) {
    bf16x8 b[4];
#pragma unroll
    for (int nj = 0; nj < 4; ++nj) b[nj] = lds8(&xs[nj * 16 + lr][kb * 32 + quad * 8]);
#pragma unroll
    for (int mi = 0; mi < 2; ++mi) {
      const bf16x8 a = *(const bf16x8*)&wqf[(size_t)(((ctv + mi) * 8 + kb) * 64 + lane) * 8];
#pragma unroll
      for (int nj = 0; nj < 4; ++nj) av[mi][nj] = MFMA16(a, b[nj], av[mi][nj]);
    }
  }
  // V bias + transpose into Vt[d][tok] (stride 72) in per-wave LDS
#pragma unroll
  for (int mi = 0; mi < 2; ++mi) {
    const f32x4 bb = *(const f32x4*)&wqkv_b[512 + h * 32 + mi * 16 + quad * 4];
#pragma unroll
    for (int nj = 0; nj < 4; ++nj)
#pragma unroll
      for (int r = 0; r < 4; ++r)
        U[(mi * 16 + quad * 4 + r) * 72 + nj * 16 + lr] = (bf16)(av[mi][nj][r] + bb[r]);
  }
  // ---- O = P @ V ----
  f32x4 o[4][2] = {};
#pragma unroll
  for (int kq = 0; kq < 2; ++kq) {
    bf16x8 vb[2];
#pragma unroll
    for (int ni = 0; ni < 2; ++ni) vb[ni] = lds8(&U[(ni * 16 + lr) * 72 + kq * 32 + quad * 8]);
#pragma unroll
    for (int mt = 0; mt < 4; ++mt)
#pragma unroll
      for (int ni = 0; ni < 2; ++ni) o[mt][ni] = MFMA16(pa[mt][kq], vb[ni], o[mt][ni]);
  }
  // pack y (bf16 pairs along r) into ob[16]
#pragma unroll
  for (int mt = 0; mt < 4; ++mt)
#pragma unroll
    for (int ni = 0; ni < 2; ++ni)
#pragma unroll
      for (int w2 = 0; w2 < 2; ++w2)
        ob[(mt * 2 + ni) * 2 + w2] = pack2(o[mt][ni][2 * w2], o[mt][ni][2 * w2 + 1]);
}

// Fused kernel: stage x -> per-wave heads -> y into xs -> output projection.
__global__ __launch_bounds__(256) void swin_fused_v4(
    const float* __restrict__ x, const bf16* __restrict__ wqf,
    const float* __restrict__ wqkv_b, const float* __restrict__ bias_table,
    const bf16* __restrict__ wpf, const float* __restrict__ wp_b,
    float* __restrict__ out) {
  __shared__ __align__(16) bf16 xs[64][264];   // x window, later reused as y
  __shared__ __align__(16) bf16 uni[4][2304];  // per-wave Vt[32][72]

  const int tid = threadIdx.x;
  const int wave = tid >> 6, lane = tid & 63;
  const int lr = lane & 15, quad = lane >> 4;
  const int win = blockIdx.x;  // [0,2048)
  const int batch = win >> 10, wy = (win >> 5) & 31, wx = win & 31;
  const int base = batch * 65536 + wy * 2048 + wx * 8;
  bf16* const U = &uni[wave][0];

  // ---- stage full x window [64 tok][256 ch] f32 -> bf16 ----
  {
    const int tok = tid >> 2, cg = (tid & 3) * 64;
    const float* xp = x + (size_t)(base + ((tok >> 3) << 8) + (tok & 7)) * 256 + cg;
#pragma unroll
    for (int g = 0; g < 8; ++g) *(bf16x8*)&xs[tok][cg + g * 8] = cvt8(xp + g * 8);
  }
  __syncthreads();  // barrier 1

  int ob0[16], ob1[16];
  attn_head(wave * 2 + 0, lane, lr, quad, (const bf16(*)[264])xs, U, wqf, wqkv_b, bias_table, ob0);
  attn_head(wave * 2 + 1, lane, lr, quad, (const bf16(*)[264])xs, U, wqf, wqkv_b, bias_table, ob1);

  __syncthreads();  // barrier 2: all waves done reading x from xs
  // ---- write y (bf16) into xs[tok][ch]; wave covers its 2 heads' 64 channels ----
#pragma unroll
  for (int rep = 0; rep < 2; ++rep) {
    const int* ob = rep ? ob1 : ob0;
    const int hh = wave * 2 + rep;
#pragma unroll
    for (int mt = 0; mt < 4; ++mt)
#pragma unroll
      for (int ni = 0; ni < 2; ++ni)
#pragma unroll
        for (int w2 = 0; w2 < 2; ++w2) {
          const bf16x2 t = __builtin_bit_cast(bf16x2, ob[(mt * 2 + ni) * 2 + w2]);
#pragma unroll
          for (int e = 0; e < 2; ++e)
            xs[mt * 16 + quad * 4 + w2 * 2 + e][hh * 32 + ni * 16 + lr] = t[e];
        }
  }
  __syncthreads();  // barrier 3: y complete
  // ---- output projection: out[64 tok][256] = y @ wp^T + b; wave owns 64 cols ----
  f32x4 ap[4][4] = {};
#pragma unroll
  for (int kb = 0; kb < 8; ++kb) {
    bf16x8 a[4], b[4];
#pragma unroll
    for (int mt = 0; mt < 4; ++mt) a[mt] = lds8(&xs[mt * 16 + lr][kb * 32 + quad * 8]);
#pragma unroll
    for (int nt = 0; nt < 4; ++nt)
      b[nt] = *(const bf16x8*)&wpf[(size_t)(((wave * 4 + nt) * 8 + kb) * 64 + lane) * 8];
#pragma unroll
    for (int mt = 0; mt < 4; ++mt)
#pragma unroll
      for (int nt = 0; nt < 4; ++nt) ap[mt][nt] = MFMA16(a[mt], b[nt], ap[mt][nt]);
  }
#pragma unroll
  for (int nt = 0; nt < 4; ++nt) {
    const int col = (wave * 4 + nt) * 16 + lr;
    const float bv = wp_b[col];
#pragma unroll
    for (int mt = 0; mt < 4; ++mt)
#pragma unroll
      for (int r = 0; r < 4; ++r) {
        const int t = mt * 16 + quad * 4 + r;
        const size_t grow = (size_t)(base + ((t >> 3) << 8) + (t & 7));
        out[grow * 256 + col] = ap[mt][nt][r] + bv;
      }
  }
}

// ======================= FALLBACK PATH (previous verified kernels) =======================

#define QS_OFF 0
#define KS_OFF 2304
#define VT_OFF 4608
#define PL_OFF 0
#define UNI_SZ 6784

__global__ __launch_bounds__(256) void fused_qkv_attn(
    const float* __restrict__ x, const float* __restrict__ wqkv_w,
    const float* __restrict__ wqkv_b, const float* __restrict__ bias_table,
    float* __restrict__ out) {
  __shared__ bf16 xs[64][72];
  __shared__ bf16 uni[4][UNI_SZ];

  const int tid = threadIdx.x;
  const int wave = tid >> 6, lane = tid & 63;
  const int lr = lane & 15, quad = lane >> 4;
  const int win = blockIdx.x;
  const int batch = win >> 10, wy = (win >> 5) & 31, wx = win & 31;
  const int base = batch * 65536 + wy * 2048 + wx * 8;
  bf16* const U = &uni[wave][0];

  const f32x4 zero = {0.f, 0.f, 0.f, 0.f};
  const float scale = 0.17677669529663687f;

  for (int rep = 0; rep < 2; rep++) {
    const int h = wave * 2 + rep;
    const int cb[6] = {h * 32,       h * 32 + 16,
                       256 + h * 32, 256 + h * 32 + 16,
                       512 + h * 32, 512 + h * 32 + 16};

    f32x4 acc[4][6] = {};
    for (int kc = 0; kc < 4; kc++) {
      __syncthreads();
      {
        const int t = tid >> 2, c0 = (tid & 3) * 16;
        const float* xp = x + (size_t)(base + (t >> 3) * 256 + (t & 7)) * 256 + kc * 64 + c0;
        *(bf16x8*)&xs[t][c0] = cvt8(xp);
        *(bf16x8*)&xs[t][c0 + 8] = cvt8(xp + 8);
      }
      __syncthreads();
#pragma unroll
      for (int k2 = 0; k2 < 64; k2 += 32) {
        bf16x8 a[4], b[6];
#pragma unroll
        for (int mi = 0; mi < 4; mi++) a[mi] = lds8(&xs[mi * 16 + lr][k2 + quad * 8]);
#pragma unroll
        for (int nj = 0; nj < 6; nj++)
          b[nj] = cvt8(wqkv_w + (size_t)(cb[nj] + lr) * 256 + kc * 64 + k2 + quad * 8);
#pragma unroll
        for (int mi = 0; mi < 4; mi++)
#pragma unroll
          for (int nj = 0; nj < 6; nj++) acc[mi][nj] = MFMA16(a[mi], b[nj], acc[mi][nj]);
      }
    }

#pragma unroll
    for (int nj = 0; nj < 6; nj++) {
      const float bv = wqkv_b[cb[nj] + lr];
#pragma unroll
      for (int mi = 0; mi < 4; mi++)
#pragma unroll
        for (int r = 0; r < 4; r++) {
          const int tok = mi * 16 + quad * 4 + r;
          const float v = acc[mi][nj][r] + bv;
          if (nj < 2)      U[QS_OFF + tok * 36 + nj * 16 + lr] = (bf16)v;
          else if (nj < 4) U[KS_OFF + tok * 36 + (nj - 2) * 16 + lr] = (bf16)v;
          else             U[VT_OFF + ((nj - 4) * 16 + lr) * 68 + tok] = (bf16)v;
        }
    }

    bf16x8 qf[4], kf[4];
#pragma unroll
    for (int i = 0; i < 4; i++) {
      qf[i] = lds8(&U[QS_OFF + (i * 16 + lr) * 36 + quad * 8]);
      kf[i] = lds8(&U[KS_OFF + (i * 16 + lr) * 36 + quad * 8]);
    }
    f32x4 s[4][4];
#pragma unroll
    for (int mi = 0; mi < 4; mi++)
#pragma unroll
      for (int nj = 0; nj < 4; nj++) s[mi][nj] = MFMA16(qf[mi], kf[nj], zero);

#pragma unroll
    for (int mi = 0; mi < 4; mi++)
#pragma unroll
      for (int nj = 0; nj < 4; nj++)
#pragma unroll
        for (int r = 0; r < 4; r++) {
          const int qt = mi * 16 + quad * 4 + r;
          const int kt = nj * 16 + lr;
          const int idx = ((qt >> 3) - (kt >> 3) + 7) * 15 + ((qt & 7) - (kt & 7) + 7);
          s[mi][nj][r] = s[mi][nj][r] * scale + bias_table[idx * 8 + h];
        }

#pragma unroll
    for (int mi = 0; mi < 4; mi++)
#pragma unroll
      for (int r = 0; r < 4; r++) {
        float mx = -1e30f;
#pragma unroll
        for (int nj = 0; nj < 4; nj++) mx = fmaxf(mx, s[mi][nj][r]);
#pragma unroll
        for (int off = 1; off < 16; off <<= 1) mx = fmaxf(mx, __shfl_xor(mx, off, 64));
        float sum = 0.f;
#pragma unroll
        for (int nj = 0; nj < 4; nj++) {
          const float e = __expf(s[mi][nj][r] - mx);
          s[mi][nj][r] = e;
          sum += e;
        }
#pragma unroll
        for (int off = 1; off < 16; off <<= 1) sum += __shfl_xor(sum, off, 64);
        const float inv = 1.0f / sum;
#pragma unroll
        for (int nj = 0; nj < 4; nj++)
          U[PL_OFF + (mi * 16 + quad * 4 + r) * 68 + nj * 16 + lr] = (bf16)(s[mi][nj][r] * inv);
      }

    f32x4 o[4][2] = {};
#pragma unroll
    for (int kq = 0; kq < 2; kq++) {
      bf16x8 pa[4], vb[2];
#pragma unroll
      for (int mi = 0; mi < 4; mi++)
        pa[mi] = lds8(&U[PL_OFF + (mi * 16 + lr) * 68 + kq * 32 + quad * 8]);
#pragma unroll
      for (int ni = 0; ni < 2; ni++)
        vb[ni] = lds8(&U[VT_OFF + (ni * 16 + lr) * 68 + kq * 32 + quad * 8]);
#pragma unroll
      for (int mi = 0; mi < 4; mi++)
#pragma unroll
        for (int ni = 0; ni < 2; ni++) o[mi][ni] = MFMA16(pa[mi], vb[ni], o[mi][ni]);
    }

#pragma unroll
    for (int mi = 0; mi < 4; mi++)
#pragma unroll
      for (int ni = 0; ni < 2; ni++)
#pragma unroll
        for (int r = 0; r < 4; r++) {
          const int t = mi * 16 + quad * 4 + r;
          const size_t row = (size_t)(base + (t >> 3) * 256 + (t & 7));
          out[row * 256 + h * 32 + ni * 16 + lr] = o[mi][ni][r];
        }
  }
}

__global__ __launch_bounds__(256) void proj_inplace(
    float* io, const float* __restrict__ W, const float* __restrict__ bias) {
  const int tid = threadIdx.x;
  const int wave = tid >> 6, lane = tid & 63;
  const int lr = lane & 15, quad = lane >> 4;
  const int row0 = blockIdx.x * 128 + (wave >> 1) * 64;
  const int col0 = (wave & 1) * 128;

  f32x4 acc[4][8] = {};
#pragma unroll
  for (int kk = 0; kk < 256; kk += 32) {
    bf16x8 a[4], b[8];
#pragma unroll
    for (int mi = 0; mi < 4; mi++)
      a[mi] = cvt8(io + (size_t)(row0 + mi * 16 + lr) * 256 + kk + quad * 8);
#pragma unroll
    for (int nj = 0; nj < 8; nj++)
      b[nj] = cvt8(W + (size_t)(col0 + nj * 16 + lr) * 256 + kk + quad * 8);
#pragma unroll
    for (int mi = 0; mi < 4; mi++)
#pragma unroll
      for (int nj = 0; nj < 8; nj++) acc[mi][nj] = MFMA16(a[mi], b[nj], acc[mi][nj]);
  }
  __syncthreads();
#pragma unroll
  for (int mi = 0; mi < 4; mi++)
#pragma unroll
    for (int nj = 0; nj < 8; nj++) {
      const int col = col0 + nj * 16 + lr;
      const float bv = bias[col];
#pragma unroll
      for (int r = 0; r < 4; r++) {
        const int row = row0 + mi * 16 + quad * 4 + r;
        io[(size_t)row * 256 + col] = acc[mi][nj][r] + bv;
      }
    }
}

extern "C" void kernel_launch(void* const* d_in, const int* in_sizes, int n_in,
                              void* d_out, int out_size, void* d_ws, size_t ws_size,
                              hipStream_t stream) {
  const float* x = (const float*)d_in[0];
  // d_in[1]=h, d_in[2]=w (fixed 256)
  const float* wqkv_w = (const float*)d_in[3];
  const float* wqkv_b = (const float*)d_in[4];
  const float* wp_w = (const float*)d_in[5];
  const float* wp_b = (const float*)d_in[6];
  const float* bias_table = (const float*)d_in[7];
  float* out = (float*)d_out;

  const size_t NEED = (size_t)(196608 + 65536) * sizeof(bf16);  // 524,288 B

  if (ws_size >= NEED) {
    bf16* wbf = (bf16*)d_ws;  // [0,196608) wqkv frag-order, [196608,262144) wp frag-order
    cvt_weights_v3<<<128, 256, 0, stream>>>(wqkv_w, wp_w, wbf);
    swin_fused_v4<<<2048, 256, 0, stream>>>(x, wbf, wqkv_b, bias_table,
                                            wbf + 196608, wp_b, out);
  } else {
    fused_qkv_attn<<<2048, 256, 0, stream>>>(x, wqkv_w, wqkv_b, bias_table, out);
    proj_inplace<<<1024, 256, 0, stream>>>(out, wp_w, wp_b);
  }
}